// Round 5
// baseline (867.188 us; speedup 1.0000x reference)
//
#include <hip/hip_runtime.h>
#include <math.h>

// TopExpertsRouter on MI355X (gfx950) — two-phase, bit-identical GEMM
// numerics to all passing rounds: per-(token,expert) logit = 8 chunks of
// ascending-512 fmaf chains (xyzw within float4), chunks summed ascending.
//
// Round-4 post-mortem: double-buffered BK=16 tiled gemm spilled acc[8][8]
// across every STAGE barrier (WRITE_SIZE 909MB vs 32MB real ~= 64 regs x 32
// subtiles x 131k threads) and my BK=16 swizzle was bank-wrong (8.4M
// conflicts; 64B row stride makes bank = 16*(row&1)+4*col4', rows 0/4
// collide). 486us.
//
// This round: the no-LDS lane=token design (best structural floor: pure
// fmac 55us, zero barriers) with the round-3 spill fixed by splitting
// experts across waves:
//   * block = 256 threads = 64 tokens x 4 expert-groups of 16 experts.
//     lane t owns token t, eg owns experts eg*16..eg*16+15 -> acc[16] only
//     (round 3 died on acc[64] -> scratch; 16+16+addr fits ~56 VGPR,
//     8 waves/SIMD).
//   * x: lane-private global b128 loads; each 128B line fully consumed over
//     2 consecutive p-iterations; the 4x eg re-read of the block's 128KB
//     x-tile is served by L1/L2 (L2 4MB/XCD).
//   * W: addresses wave-uniform (compile-time e, uniform p/chunk) -> scalar
//     s_load on the scalar pipe, v_fmac_f32 acc, s_w, v_x (1 SGPR legal).
//   * zero LDS, zero __syncthreads, 16 independent chains = full ILP.
//   * partial[chunk][e][token]: lanes = consecutive tokens -> 256B stores.
// Accumulation per acc: ascending d=0..511 of its chunk (32 pieces x 16,
// xyzw) — identical chain to every passing round. Finish kernel = round-4's
// (passed; parallel 4-lane/token epilogue with exact tie-break).

constexpr int D  = 4096;
constexpr int E  = 64;
constexpr int K  = 8;

__global__ __launch_bounds__(256, 4) void router_gemm(
    const float* __restrict__ x, const float* __restrict__ W,
    float* __restrict__ partial, int ntok, int dlen, int ntiles)
{
    // ntiles = ntok/64 token-blocks; grid = ntiles * nchunks
    const int tid   = threadIdx.x;
    const int tile  = blockIdx.x % ntiles;
    const int chunk = blockIdx.x / ntiles;
    const int tl  = tid & 63;            // token lane
    const int eg  = tid >> 6;            // expert group 0..3
    const int t   = tile * 64 + tl;
    const int d0  = chunk * dlen;
    const int e0  = eg * 16;

    const float* xp = x + (size_t)t * D + d0;
    const float* Wc = W + (size_t)e0 * D + d0;   // uniform per wave

    float acc[16];
#pragma unroll
    for (int e = 0; e < 16; ++e) acc[e] = 0.f;

    const int np = dlen / 16;            // 32 pieces of 16 dims
    for (int p = 0; p < np; ++p) {
        float4 xv[4];
#pragma unroll
        for (int q = 0; q < 4; ++q)
            xv[q] = *(const float4*)(xp + p * 16 + q * 4);

        const float* wp = Wc + p * 16;   // wave-uniform
#pragma unroll
        for (int e = 0; e < 16; ++e) {
            const float* w = wp + (size_t)e * D;   // uniform -> s_load
            float a = acc[e];
            a = fmaf(xv[0].x, w[0],  a);
            a = fmaf(xv[0].y, w[1],  a);
            a = fmaf(xv[0].z, w[2],  a);
            a = fmaf(xv[0].w, w[3],  a);
            a = fmaf(xv[1].x, w[4],  a);
            a = fmaf(xv[1].y, w[5],  a);
            a = fmaf(xv[1].z, w[6],  a);
            a = fmaf(xv[1].w, w[7],  a);
            a = fmaf(xv[2].x, w[8],  a);
            a = fmaf(xv[2].y, w[9],  a);
            a = fmaf(xv[2].z, w[10], a);
            a = fmaf(xv[2].w, w[11], a);
            a = fmaf(xv[3].x, w[12], a);
            a = fmaf(xv[3].y, w[13], a);
            a = fmaf(xv[3].z, w[14], a);
            a = fmaf(xv[3].w, w[15], a);
            acc[e] = a;
        }
    }

    // partial[chunk][e][token]: lanes hold consecutive tokens -> coalesced
    float* dst = partial + ((size_t)chunk * E + e0) * ntok + t;
#pragma unroll
    for (int e = 0; e < 16; ++e)
        dst[(size_t)e * ntok] = acc[e];
}

template <int NC>
__global__ __launch_bounds__(256) void router_finish(
    const float* __restrict__ partial, float* __restrict__ out, int ntok)
{
    __shared__ float ls[64][E + 4];

    const int tid = threadIdx.x;
    const int t0  = blockIdx.x * 64;

    // ---- phase 1: float4 over tokens; chunks summed ascending (bit-equal) --
    const int t4 = tid & 15;         // token quad: tokens t4*4 .. t4*4+3
    const int eb = tid >> 4;         // 0..15
#pragma unroll
    for (int g = 0; g < 4; ++g) {
        const int e = eb + 16 * g;
        const float* p = partial + (size_t)e * ntok + t0 + t4 * 4;
        float4 a = *(const float4*)p;
#pragma unroll
        for (int c = 1; c < NC; ++c) {
            const float4 b = *(const float4*)(p + (size_t)c * E * ntok);
            a.x += b.x; a.y += b.y; a.z += b.z; a.w += b.w;
        }
        ls[t4 * 4 + 0][e] = a.x;
        ls[t4 * 4 + 1][e] = a.y;
        ls[t4 * 4 + 2][e] = a.z;
        ls[t4 * 4 + 3][e] = a.w;
    }
    __syncthreads();

    // ---- phase 2: 4 lanes per token ----
    const int tt = tid >> 2;         // token 0..63
    const int q  = tid & 3;          // expert quarter: e = q*16 + eo
    const int n  = t0 + tt;

    float v[16];
#pragma unroll
    for (int g = 0; g < 4; ++g) {
        const float4 r = *(const float4*)&ls[tt][q * 16 + g * 4];
        v[g * 4 + 0] = r.x; v[g * 4 + 1] = r.y;
        v[g * 4 + 2] = r.z; v[g * 4 + 3] = r.w;
    }

    // max: bit-exact (fmax is order-independent)
    float m = v[0];
#pragma unroll
    for (int e = 1; e < 16; ++e) m = fmaxf(m, v[e]);
    m = fmaxf(m, __shfl_xor(m, 1));
    m = fmaxf(m, __shfl_xor(m, 2));

    // exp + sum (lane-partial ascending, then butterfly — common scale/token)
    float s = 0.f;
#pragma unroll
    for (int e = 0; e < 16; ++e) { v[e] = expf(v[e] - m); s += v[e]; }
    s += __shfl_xor(s, 1);
    s += __shfl_xor(s, 2);
    const float inv = 1.f / s;
#pragma unroll
    for (int e = 0; e < 16; ++e) v[e] *= inv;

    float* probs = out + (size_t)ntok * 2 * K + (size_t)n * E;
#pragma unroll
    for (int g = 0; g < 4; ++g)
        *(float4*)&probs[q * 16 + g * 4] =
            make_float4(v[g * 4], v[g * 4 + 1], v[g * 4 + 2], v[g * 4 + 3]);

    // top-8: lane-local first-max over 16, then 2-step merge preferring
    // (greater) | (equal & lower index) — identical to serial ascending scan.
    float vals[K];
    int   idxs[K];
    float ts = 0.f;
    for (int k = 0; k < K; ++k) {
        float b  = v[0];
        int   bi = q * 16;
#pragma unroll
        for (int e = 1; e < 16; ++e)
            if (v[e] > b) { b = v[e]; bi = q * 16 + e; }
        float ob;
        int   obi;
        ob  = __shfl_xor(b, 1);
        obi = __shfl_xor(bi, 1);
        if (ob > b || (ob == b && obi < bi)) { b = ob; bi = obi; }
        ob  = __shfl_xor(b, 2);
        obi = __shfl_xor(bi, 2);
        if (ob > b || (ob == b && obi < bi)) { b = ob; bi = obi; }
        vals[k] = b;
        idxs[k] = bi;
        ts += b;
        const int lo = bi - q * 16;      // mask owner's copy (unrolled cmp)
#pragma unroll
        for (int e = 0; e < 16; ++e)
            if (e == lo) v[e] = -1.f;    // lo in [0,16) only for owning lane
    }
    const float winv = 1.f / (ts + 1e-9f);

    if (q == 0) {
        float* oi = out + (size_t)n * K;
        float* ow = out + (size_t)ntok * K + (size_t)n * K;
#pragma unroll
        for (int k = 0; k < K; ++k) {
            oi[k] = (float)idxs[k];
            ow[k] = vals[k] * winv;
        }
    }
}

extern "C" void kernel_launch(void* const* d_in, const int* in_sizes, int n_in,
                              void* d_out, int out_size, void* d_ws, size_t ws_size,
                              hipStream_t stream)
{
    const float* x = (const float*)d_in[0];
    const float* W = (const float*)d_in[1];
    float* out = (float*)d_out;

    const int ntok = in_sizes[0] / D;  // 16384

    // identical nchunks policy to passing rounds (bit-exactness anchor)
    int nchunks = 8;
    while (nchunks > 1 &&
           (size_t)nchunks * E * (size_t)ntok * sizeof(float) > ws_size)
        nchunks >>= 1;
    const int dlen   = D / nchunks;
    const int ntiles = ntok / 64;      // 64 tokens per gemm block

    float* partial = (float*)d_ws;

    hipLaunchKernelGGL(router_gemm, dim3(ntiles * nchunks), dim3(256), 0, stream,
                       x, W, partial, ntok, dlen, ntiles);
    switch (nchunks) {
        case 8:
            hipLaunchKernelGGL(router_finish<8>, dim3(ntok / 64), dim3(256), 0,
                               stream, partial, out, ntok);
            break;
        case 4:
            hipLaunchKernelGGL(router_finish<4>, dim3(ntok / 64), dim3(256), 0,
                               stream, partial, out, ntok);
            break;
        case 2:
            hipLaunchKernelGGL(router_finish<2>, dim3(ntok / 64), dim3(256), 0,
                               stream, partial, out, ntok);
            break;
        default:
            hipLaunchKernelGGL(router_finish<1>, dim3(ntok / 64), dim3(256), 0,
                               stream, partial, out, ntok);
            break;
    }
}